// Round 8
// baseline (284.814 us; speedup 1.0000x reference)
//
#include <hip/hip_runtime.h>

#define N_DATA   128
#define SEG_LEN  131072
#define NPROD    (SEG_LEN - 1)
#define N_MAT    8
#define N_MATP   8
#define N_PROCP  5
#define RGAS     8.314f

#define TPB      256
#define RUNS     8                    // runs of 4 elements per lane
#define EPT      (RUNS * 4)           // 32 elements per lane
#define WCHUNK   (64 * EPT)           // 2048 elements per wave
#define WPR      (SEG_LEN / WCHUNK)   // 64 wave-slots per row
#define NWAVE    (N_DATA * WPR)       // 8192 waves = 256 CU x 32: one generation
#define NBLK     (NWAVE / (TPB / 64)) // 2048 blocks
#define NSLOT    NWAVE                // packed {ready|sum} slots
#define NINIT    (NSLOT + N_DATA)     // + 128 row masks

typedef float nt4 __attribute__((ext_vector_type(4)));  // native vec for nontemporal builtin

// K0: re-arm packed slots AND row masks (workspace re-poisoned between
// iterations; poison bits could fake "ready"). Kernel => graph-capture-safe.
__global__ __launch_bounds__(TPB) void k0_init(unsigned long long* __restrict__ cs) {
  int i = blockIdx.x * TPB + threadIdx.x;
  if (i < NINIT) cs[i] = 0ull;
}

// Single-pass scan, WAVE-grained, zero barriers, zero LDS, dense memory ops,
// fence-free sync, QUIET spin.
//
// Round-6 residual diagnosed: per-lane slot polling = ~512B of LLC-bypass
// atomic loads per wave per ~235ns retry across ~8192 parked waves
// = ~18 TB/s of Infinity-Cache request traffic -- saturates the fabric that
// serves the L3-resident x reads (HBM pinned at 2.2 TB/s, VALU 39%).
//
// Sync protocol (lessons 4/5/6 baked in):
//   publish: lane0 relaxed-stores packed {ready<<32|bits} to cs[row*64+s]
//            (single word => no fence; round-5's agent fences = whole-L2
//            writeback on gfx950, 7x regression), then relaxed atomic-ORs
//            bit s into mask[row] -- ADVISORY only, no ordering needed.
//   wait:    spin on ONE wave-uniform 8B load of mask[row] per retry
//            (64 lanes same address = 1 fabric transaction, 64x less spin
//            traffic than per-lane slot polling), s_sleep(2) between.
//   gather:  lane l < s loads cs slot l ONCE; slot self-validates via its
//            ready bit (micro-spin only on the mask-raced-ahead window);
//            full-exec butterfly reduce -> row offset.
// Predecessors have lower blockIdx => in-order dispatch => resident
// (one-generation sizing) or retired (rocPRIM forward-progress assumption).
//
// CORRECTNESS (round-3 lesson): every __shfl executes in FULL exec; only
// loads/selects sit in divergent code.
__global__ __launch_bounds__(TPB) void k_scan(
    const float* __restrict__ x,
    const float* __restrict__ pc, const float* __restrict__ raw,
    const float* __restrict__ lb, const float* __restrict__ ub,
    const float* __restrict__ sc, const int* __restrict__ mat_idx,
    unsigned long long* __restrict__ cs,
    unsigned long long* __restrict__ mask,
    float* __restrict__ out) {
  int tid  = threadIdx.x;
  int lane = tid & 63;
  int w    = blockIdx.x * (TPB >> 6) + (tid >> 6);     // global wave id
  int row  = __builtin_amdgcn_readfirstlane(w >> 6);   // wave-uniform -> SGPR
  int s    = __builtin_amdgcn_readfirstlane(w & (WPR - 1));

  // issue x loads immediately (fly during param compute); lane-contiguous
  long rowbase = (long)row * SEG_LEN;
  int  gb0 = s * WCHUNK;                               // row-local wave base
  const float* xp = x + rowbase + gb0 + lane * 4;
  float4 v[RUNS];
#pragma unroll
  for (int r = 0; r < RUNS; r++) v[r] = *(const float4*)(xp + r * 256);
  float xe = 0.0f;                                     // cross-wave edge
  if (lane == 63 && gb0 + WCHUNK < SEG_LEN) xe = x[rowbase + gb0 + WCHUNK];

  // param transform: lanes 0..12 compute one sigmoid each; broadcast by shfl
  float pvl = 0.0f;
  if (lane < 13) {
    int idx = (lane < 5) ? (N_MAT * N_MATP + row * N_PROCP + lane)
                         : (mat_idx[row] * N_MATP + (lane - 5));
    float sg = 1.0f / (1.0f + __expf(-raw[idx]));
    pvl = sg * (ub[idx] - lb[idx]) + lb[idx];
  }
  float SigmaC = __shfl(pvl, 0),  K0   = __shfl(pvl, 1), alpha1 = __shfl(pvl, 2);
  float L0     = __shfl(pvl, 3),  G200 = __shfl(pvl, 4);
  float Sigma0 = __shfl(pvl, 5),  BetaD = __shfl(pvl, 6), Ea = __shfl(pvl, 7);
  float Mfda   = __shfl(pvl, 8),  Di   = __shfl(pvl, 9);
  float A0     = __shfl(pvl, 10), B0   = __shfl(pvl, 11), l0 = __shfl(pvl, 12);

  float R = pc[row * 4 + 0], T = pc[row * 4 + 1], P = pc[row * 4 + 2];
  float cbd      = BetaD * Di * __expf(-Ea / (RGAS * T));
  float base_num = SigmaC - Mfda * P;
  float inv_tau  = 1.0f / (B0 * l0 + 1e-9f);
  float x_min = sc[0], x_sc = sc[1] - sc[0];
  float y_min = sc[2], inv_yr = 1.0f / (sc[3] - sc[2]);

  // x -> t
  float t[RUNS][4];
#pragma unroll
  for (int r = 0; r < RUNS; r++) {
    t[r][0] = v[r].x * x_sc + x_min;
    t[r][1] = v[r].y * x_sc + x_min;
    t[r][2] = v[r].z * x_sc + x_min;
    t[r][3] = v[r].w * x_sc + x_min;
  }

  // t_next for each run's last element: ALL shuffles full-exec, then select.
  float nx[RUNS];
  {
    float dsh[RUNS], bc[RUNS];
#pragma unroll
    for (int r = 0; r < RUNS; r++) dsh[r] = __shfl_down(t[r][0], 1);
#pragma unroll
    for (int r = 0; r < RUNS - 1; r++) bc[r] = __shfl(t[r + 1][0], 0);
    bc[RUNS - 1] = xe * x_sc + x_min;   // valid on lane 63 (only user)
    bool last = (lane == 63);
#pragma unroll
    for (int r = 0; r < RUNS; r++) nx[r] = last ? bc[r] : dsh[r];
  }

  // products, in place over t (t[r][k] dead after its product is computed)
  int glb = gb0 + lane * 4;   // row-local index of run-0 element 0
  float rs[RUNS];
#pragma unroll
  for (int r = 0; r < RUNS; r++) {
    float acc = 0.0f;
#pragma unroll
    for (int k = 0; k < 4; k++) {
      float tn = (k < 3) ? t[r][k + 1] : nx[r];
      float pp = 0.0f;
      if (glb + r * 256 + k < NPROD) {
        float Lg = G200 * __expf(alpha1 * __logf(t[r][k] * (1.0f / 200.0f) + 0.001f)) + L0;
        float u  = R * Lg + 1e-9f;
        float num = (base_num * u) * Lg + Sigma0 * cbd;
        float den = Lg * (u + cbd);
        float ss  = num * __builtin_amdgcn_rcpf(den)
                  + A0 * __expf(-t[r][k] * inv_tau);
        pp = ss * (tn - t[r][k]);
      }
      acc += pp;
      t[r][k] = pp;           // t now holds products
    }
    rs[r] = acc;
  }

  // wave total via butterfly -> publish ASAP (before scan work)
  float tot = rs[0] + rs[1] + rs[2] + rs[3] + rs[4] + rs[5] + rs[6] + rs[7];
#pragma unroll
  for (int d = 1; d < 64; d <<= 1) tot += __shfl_xor(tot, d);
  if (lane == 0) {
    unsigned long long u = (1ull << 32) |
        (unsigned long long)__float_as_uint(tot);
    __hip_atomic_store(cs + ((row << 6) + s), u,
                       __ATOMIC_RELAXED, __HIP_MEMORY_SCOPE_AGENT);
    __hip_atomic_fetch_or(mask + row, 1ull << s,
                          __ATOMIC_RELAXED, __HIP_MEMORY_SCOPE_AGENT);
  }

  // 8 chained inclusive wave-scans -> per-run exclusive prefixes.
  // This VALU/DS work overlaps predecessors' publish latency.
  float e[RUNS];
  float carry = 0.0f;
#pragma unroll
  for (int r = 0; r < RUNS; r++) {
    float inc = rs[r];
#pragma unroll
    for (int d = 1; d < 64; d <<= 1) {
      float nn = __shfl_up(inc, d);
      if (lane >= d) inc += nn;
    }
    e[r] = carry + inc - rs[r];
    carry += __shfl(inc, 63);
  }

  // pre-scale store values in place (row offset folded in after the wait)
#pragma unroll
  for (int r = 0; r < RUNS; r++) {
    float c0 = K0 + e[r] - y_min;
    float c1 = c0 + t[r][0];
    float c2 = c1 + t[r][1];
    float c3 = c2 + t[r][2];
    t[r][0] = c0 * inv_yr; t[r][1] = c1 * inv_yr;
    t[r][2] = c2 * inv_yr; t[r][3] = c3 * inv_yr;
  }

  // QUIET wait: wave-uniform single-transaction spin on the row mask.
  // s is SGPR -> branch is wave-uniform; no shuffles inside.
  if (s > 0) {
    unsigned long long need = (1ull << s) - 1ull;
    const unsigned long long* mp = mask + row;
    unsigned long long m = __hip_atomic_load(mp, __ATOMIC_RELAXED,
                                             __HIP_MEMORY_SCOPE_AGENT);
    while ((m & need) != need) {
      __builtin_amdgcn_s_sleep(2);
      m = __hip_atomic_load(mp, __ATOMIC_RELAXED, __HIP_MEMORY_SCOPE_AGENT);
    }
  }
  // one-shot gather; each slot self-validates (mask is advisory only)
  float vv = 0.0f;
  if (lane < s) {
    const unsigned long long* p = cs + ((row << 6) + lane);
    unsigned long long u = __hip_atomic_load(p, __ATOMIC_RELAXED,
                                             __HIP_MEMORY_SCOPE_AGENT);
    while (!(unsigned)(u >> 32)) {      // mask bit raced ahead: ~never
      __builtin_amdgcn_s_sleep(1);
      u = __hip_atomic_load(p, __ATOMIC_RELAXED, __HIP_MEMORY_SCOPE_AGENT);
    }
    vv = __uint_as_float((unsigned)u);
  }
#pragma unroll
  for (int d = 32; d > 0; d >>= 1) vv += __shfl_down(vv, d);   // full exec
  float choff = __shfl(vv, 0) * inv_yr;        // already output-scaled

  // dense nontemporal stores: lane i at base + i*16B, 1024B per instruction
  float* ob = out + rowbase + gb0 + lane * 4;
#pragma unroll
  for (int r = 0; r < RUNS; r++) {
    nt4 o;
    o.x = t[r][0] + choff; o.y = t[r][1] + choff;
    o.z = t[r][2] + choff; o.w = t[r][3] + choff;
    __builtin_nontemporal_store(o, (nt4*)(ob + r * 256));  // out never re-read
  }
}

extern "C" void kernel_launch(void* const* d_in, const int* in_sizes, int n_in,
                              void* d_out, int out_size, void* d_ws, size_t ws_size,
                              hipStream_t stream) {
  const float* x_scaled  = (const float*)d_in[0];
  const float* process_c = (const float*)d_in[1];
  const float* raw       = (const float*)d_in[2];
  const float* lb        = (const float*)d_in[3];
  const float* ub        = (const float*)d_in[4];
  const float* sc        = (const float*)d_in[5];
  // d_in[6] = fit_index (unused by the reference computation)
  const int*   mat_idx   = (const int*)d_in[7];
  float* out = (float*)d_out;
  unsigned long long* cs   = (unsigned long long*)d_ws;  // 8192 packed {ready|sum}
  unsigned long long* mask = cs + NSLOT;                 // 128 row masks

  k0_init<<<(NINIT + TPB - 1) / TPB, TPB, 0, stream>>>(cs);
  k_scan<<<NBLK, TPB, 0, stream>>>(
      x_scaled, process_c, raw, lb, ub, sc, mat_idx, cs, mask, out);
}

// Round 9
// 173.197 us; speedup vs baseline: 1.6445x; 1.6445x over previous
//
#include <hip/hip_runtime.h>

#define N_DATA   128
#define SEG_LEN  131072
#define NPROD    (SEG_LEN - 1)
#define N_MAT    8
#define N_MATP   8
#define N_PROCP  5
#define RGAS     8.314f

#define TPB      256
#define RUNS     8                    // runs of 4 elements per lane
#define EPT      (RUNS * 4)           // 32 elements per lane
#define WCHUNK   (64 * EPT)           // 2048 elements per wave
#define WPR      (SEG_LEN / WCHUNK)   // 64 wave-slots per row
#define NWAVE    (N_DATA * WPR)       // 8192 waves = 256 CU x 32: one generation
#define NBLK     (NWAVE / (TPB / 64)) // 2048 blocks

typedef float nt4 __attribute__((ext_vector_type(4)));  // native vec for nontemporal builtin

// K0: re-arm the packed {ready|value} words (workspace is re-poisoned between
// iterations; poison bits could fake "ready"). Kernel => graph-capture-safe.
__global__ __launch_bounds__(TPB) void k0_init(unsigned long long* __restrict__ cs) {
  cs[blockIdx.x * TPB + threadIdx.x] = 0ull;
}

// Single-pass scan, WAVE-grained, zero barriers, zero LDS, dense memory ops,
// fence-free sync. Wave w owns elements [w*2048, w*2048+2048). Lane i owns
// 8 runs of 4 at wavebase + r*256 + i*4 => every dwordx4 load/store is
// lane-dense (1024B per instruction).
//
// Sync protocol -- accumulated lessons:
//  R3: every __shfl in FULL exec; only loads/selects in divergent code.
//  R5: flag+value in ONE u64 ({ready<<32|bits}), relaxed agent atomics, NO
//      fences (agent fences = whole-L2 writeback on gfx950: 7x regression).
//  R8: producers use plain stores to DISJOINT slots; shared-word RMW
//      publish (atomicOr mask) serializes at the LLC and is 3.4x worse.
//  R9: consumer retry rate matters -- fixed 64-cyc retry across ~4000
//      parked waves = multi-TB/s of LLC spin traffic stealing fabric from
//      the load stream. Staged exponential backoff (1,2,4 then 8) cuts it
//      ~8x; first check stays immediate so resolved slots cost nothing.
__global__ __launch_bounds__(TPB) void k_scan(
    const float* __restrict__ x,
    const float* __restrict__ pc, const float* __restrict__ raw,
    const float* __restrict__ lb, const float* __restrict__ ub,
    const float* __restrict__ sc, const int* __restrict__ mat_idx,
    unsigned long long* __restrict__ cs,
    float* __restrict__ out) {
  int tid  = threadIdx.x;
  int lane = tid & 63;
  int w    = blockIdx.x * (TPB >> 6) + (tid >> 6);     // global wave id
  int row  = __builtin_amdgcn_readfirstlane(w >> 6);   // wave-uniform -> SGPR
  int s    = __builtin_amdgcn_readfirstlane(w & (WPR - 1));

  // issue x loads immediately (fly during param compute); lane-contiguous
  long rowbase = (long)row * SEG_LEN;
  int  gb0 = s * WCHUNK;                               // row-local wave base
  const float* xp = x + rowbase + gb0 + lane * 4;
  float4 v[RUNS];
#pragma unroll
  for (int r = 0; r < RUNS; r++) v[r] = *(const float4*)(xp + r * 256);
  float xe = 0.0f;                                     // cross-wave edge
  if (lane == 63 && gb0 + WCHUNK < SEG_LEN) xe = x[rowbase + gb0 + WCHUNK];

  // param transform: lanes 0..12 compute one sigmoid each; broadcast by shfl
  float pvl = 0.0f;
  if (lane < 13) {
    int idx = (lane < 5) ? (N_MAT * N_MATP + row * N_PROCP + lane)
                         : (mat_idx[row] * N_MATP + (lane - 5));
    float sg = 1.0f / (1.0f + __expf(-raw[idx]));
    pvl = sg * (ub[idx] - lb[idx]) + lb[idx];
  }
  float SigmaC = __shfl(pvl, 0),  K0   = __shfl(pvl, 1), alpha1 = __shfl(pvl, 2);
  float L0     = __shfl(pvl, 3),  G200 = __shfl(pvl, 4);
  float Sigma0 = __shfl(pvl, 5),  BetaD = __shfl(pvl, 6), Ea = __shfl(pvl, 7);
  float Mfda   = __shfl(pvl, 8),  Di   = __shfl(pvl, 9);
  float A0     = __shfl(pvl, 10), B0   = __shfl(pvl, 11), l0 = __shfl(pvl, 12);

  float R = pc[row * 4 + 0], T = pc[row * 4 + 1], P = pc[row * 4 + 2];
  float cbd      = BetaD * Di * __expf(-Ea / (RGAS * T));
  float base_num = SigmaC - Mfda * P;
  float inv_tau  = 1.0f / (B0 * l0 + 1e-9f);
  float x_min = sc[0], x_sc = sc[1] - sc[0];
  float y_min = sc[2], inv_yr = 1.0f / (sc[3] - sc[2]);

  // x -> t
  float t[RUNS][4];
#pragma unroll
  for (int r = 0; r < RUNS; r++) {
    t[r][0] = v[r].x * x_sc + x_min;
    t[r][1] = v[r].y * x_sc + x_min;
    t[r][2] = v[r].z * x_sc + x_min;
    t[r][3] = v[r].w * x_sc + x_min;
  }

  // t_next for each run's last element: ALL shuffles full-exec, then select.
  float nx[RUNS];
  {
    float dsh[RUNS], bc[RUNS];
#pragma unroll
    for (int r = 0; r < RUNS; r++) dsh[r] = __shfl_down(t[r][0], 1);
#pragma unroll
    for (int r = 0; r < RUNS - 1; r++) bc[r] = __shfl(t[r + 1][0], 0);
    bc[RUNS - 1] = xe * x_sc + x_min;   // valid on lane 63 (only user)
    bool last = (lane == 63);
#pragma unroll
    for (int r = 0; r < RUNS; r++) nx[r] = last ? bc[r] : dsh[r];
  }

  // products, in place over t. Guard hoist: the < NPROD test can only fail
  // in the LAST slot of a row (row-local index NPROD occurs at s==WPR-1).
  // s is SGPR -> wave-uniform branch; compiler clones guarded/unguarded.
  int glb = gb0 + lane * 4;   // row-local index of run-0 element 0
  float rs[RUNS];
  auto do_prod = [&](bool tail) {
#pragma unroll
    for (int r = 0; r < RUNS; r++) {
      float acc = 0.0f;
#pragma unroll
      for (int k = 0; k < 4; k++) {
        float tn = (k < 3) ? t[r][k + 1] : nx[r];
        float Lg = G200 * __expf(alpha1 * __logf(t[r][k] * (1.0f / 200.0f) + 0.001f)) + L0;
        float u  = R * Lg + 1e-9f;
        float num = (base_num * u) * Lg + Sigma0 * cbd;
        float den = Lg * (u + cbd);
        float ss  = num * __builtin_amdgcn_rcpf(den)
                  + A0 * __expf(-t[r][k] * inv_tau);
        float pp = ss * (tn - t[r][k]);
        if (tail && (glb + r * 256 + k >= NPROD)) pp = 0.0f;
        acc += pp;
        t[r][k] = pp;         // t now holds products
      }
      rs[r] = acc;
    }
  };
  if (s == WPR - 1) do_prod(true); else do_prod(false);

  // wave total via butterfly -> publish ASAP (before scan work).
  // Plain relaxed store to a DISJOINT slot (R8 lesson: no shared-word RMW).
  float tot = rs[0] + rs[1] + rs[2] + rs[3] + rs[4] + rs[5] + rs[6] + rs[7];
#pragma unroll
  for (int d = 1; d < 64; d <<= 1) tot += __shfl_xor(tot, d);
  if (lane == 0) {
    unsigned long long u = (1ull << 32) |
        (unsigned long long)__float_as_uint(tot);
    __hip_atomic_store(cs + ((row << 6) + s), u,
                       __ATOMIC_RELAXED, __HIP_MEMORY_SCOPE_AGENT);
  }

  // 8 chained inclusive wave-scans -> per-run exclusive prefixes.
  // This VALU/DS work overlaps predecessors' publish latency.
  float e[RUNS];
  float carry = 0.0f;
#pragma unroll
  for (int r = 0; r < RUNS; r++) {
    float inc = rs[r];
#pragma unroll
    for (int d = 1; d < 64; d <<= 1) {
      float nn = __shfl_up(inc, d);
      if (lane >= d) inc += nn;
    }
    e[r] = carry + inc - rs[r];
    carry += __shfl(inc, 63);
  }

  // pre-scale store values in place (row offset folded in after the wait)
#pragma unroll
  for (int r = 0; r < RUNS; r++) {
    float c0 = K0 + e[r] - y_min;
    float c1 = c0 + t[r][0];
    float c2 = c1 + t[r][1];
    float c3 = c2 + t[r][2];
    t[r][0] = c0 * inv_yr; t[r][1] = c1 * inv_yr;
    t[r][2] = c2 * inv_yr; t[r][3] = c3 * inv_yr;
  }

  // wait + gather: lane l < s polls exactly one packed slot (WPR=64).
  // Staged exponential backoff: immediate check, then sleeps 1,2,4, then 8.
  // s_sleep needs an immediate => unrolled stages. Divergent region holds
  // ONLY loads; shuffles follow in full exec (R3 rule). Resolved lanes
  // exec-mask out of the loop, so spin traffic decays as slots land.
  float vv = 0.0f;
  if (lane < s) {
    const unsigned long long* p = cs + ((row << 6) + lane);
    unsigned long long u = __hip_atomic_load(p, __ATOMIC_RELAXED,
                                             __HIP_MEMORY_SCOPE_AGENT);
    if (!(unsigned)(u >> 32)) {
      __builtin_amdgcn_s_sleep(1);
      u = __hip_atomic_load(p, __ATOMIC_RELAXED, __HIP_MEMORY_SCOPE_AGENT);
    }
    if (!(unsigned)(u >> 32)) {
      __builtin_amdgcn_s_sleep(2);
      u = __hip_atomic_load(p, __ATOMIC_RELAXED, __HIP_MEMORY_SCOPE_AGENT);
    }
    if (!(unsigned)(u >> 32)) {
      __builtin_amdgcn_s_sleep(4);
      u = __hip_atomic_load(p, __ATOMIC_RELAXED, __HIP_MEMORY_SCOPE_AGENT);
    }
    while (!(unsigned)(u >> 32)) {
      __builtin_amdgcn_s_sleep(8);
      u = __hip_atomic_load(p, __ATOMIC_RELAXED, __HIP_MEMORY_SCOPE_AGENT);
    }
    vv = __uint_as_float((unsigned)u);
  }
#pragma unroll
  for (int d = 32; d > 0; d >>= 1) vv += __shfl_down(vv, d);   // full exec
  float choff = __shfl(vv, 0) * inv_yr;        // already output-scaled

  // dense nontemporal stores: lane i at base + i*16B, 1024B per instruction
  float* ob = out + rowbase + gb0 + lane * 4;
#pragma unroll
  for (int r = 0; r < RUNS; r++) {
    nt4 o;
    o.x = t[r][0] + choff; o.y = t[r][1] + choff;
    o.z = t[r][2] + choff; o.w = t[r][3] + choff;
    __builtin_nontemporal_store(o, (nt4*)(ob + r * 256));  // out never re-read
  }
}

extern "C" void kernel_launch(void* const* d_in, const int* in_sizes, int n_in,
                              void* d_out, int out_size, void* d_ws, size_t ws_size,
                              hipStream_t stream) {
  const float* x_scaled  = (const float*)d_in[0];
  const float* process_c = (const float*)d_in[1];
  const float* raw       = (const float*)d_in[2];
  const float* lb        = (const float*)d_in[3];
  const float* ub        = (const float*)d_in[4];
  const float* sc        = (const float*)d_in[5];
  // d_in[6] = fit_index (unused by the reference computation)
  const int*   mat_idx   = (const int*)d_in[7];
  float* out = (float*)d_out;
  unsigned long long* cs = (unsigned long long*)d_ws;  // 8192 packed {ready|sum}

  k0_init<<<NWAVE / TPB, TPB, 0, stream>>>(cs);
  k_scan<<<NBLK, TPB, 0, stream>>>(
      x_scaled, process_c, raw, lb, ub, sc, mat_idx, cs, out);
}